// Round 5
// baseline (344.125 us; speedup 1.0000x reference)
//
#include <hip/hip_runtime.h>
#include <hip/hip_bf16.h>

// N=8192, D=512.  Q = emb@Wqk^T+bqk (K==Q); out = softmax(QK^T/sqrt(512)) @ V.
// Softmax rows sum to 1 => out = (softmax(S)@emb) @ Wv^T + bv (V never built).
// R19: attn128 (211us) confirmed at its structural plateau (R18: halving
// FETCH via XCD remap changed nothing -> LDS/MFMA-pipe bound; conflict count
// = b128 8-phase floor). Satellites were 101us across 4 serial dispatches and
// did NOT respond to 2x block count -> dispatch-count bound. R19 cuts the
// pipeline 5->3 dispatches: detect_kernel inlined as a wave-uniform probe;
// prep_kernel eliminated (projqT/finalize read fp32 weights directly with
// per-use RNE conversion — the proven projq-fallback pattern; L2-hot).
// attn128 byte-identical to R17/R18. Fallback tiers unchanged.

#define NTOK 8192
#define DIM  512

typedef unsigned short ushort_t;
typedef unsigned int u32;
typedef __attribute__((ext_vector_type(8))) __bf16 bf16x8;
typedef __attribute__((ext_vector_type(4))) float f32x4;

__device__ __forceinline__ float bf2f(ushort_t u) {
    union { unsigned int i; float f; } v; v.i = ((unsigned int)u) << 16; return v.f;
}
__device__ __forceinline__ ushort_t f2bf(float f) {
    union { float f; unsigned int i; } v; v.f = f;
    unsigned int b = v.i;
    return (ushort_t)((b + 0x7FFFu + ((b >> 16) & 1u)) >> 16);   // RNE
}
__device__ __forceinline__ __bf16 f2bfh(float f) {
    union { ushort_t u; __bf16 h; } c; c.u = f2bf(f); return c.h;
}
__device__ __forceinline__ f32x4 mfma16(bf16x8 a, bf16x8 b, f32x4 c) {
    return __builtin_amdgcn_mfma_f32_16x16x32_bf16(a, b, c, 0, 0, 0);
}
__device__ __forceinline__ bf16x8 load8(const void* p, size_t idx, bool f32) {
    if (f32) {
        const float* f = (const float*)p + idx;
        bf16x8 r;
        #pragma unroll
        for (int j = 0; j < 8; ++j) r[j] = f2bfh(f[j]);
        return r;
    }
    return *(const bf16x8*)((const ushort_t*)p + idx);
}
__device__ __forceinline__ float loadS(const void* p, size_t idx, bool f32) {
    return f32 ? ((const float*)p)[idx] : bf2f(((const ushort_t*)p)[idx]);
}
__device__ __forceinline__ void gload_lds16(const ushort_t* g, ushort_t* l) {
    __builtin_amdgcn_global_load_lds(
        (const __attribute__((address_space(1))) u32*)g,
        (__attribute__((address_space(3))) u32*)l, 16, 0, 0);
}

// Inline dtype probe (replaces detect_kernel in the top tier): every wave
// samples the SAME 512 ushorts of emb -> identical count per wave ->
// block-uniform result with no cross-wave sync. Matches detect_kernel's
// heuristic exactly: f32 iff bf16-pattern count < 460.
__device__ __forceinline__ bool probe_f32(const ushort_t* emb) {
    int lane = threadIdx.x & 63;
    int cnt = 0;
    #pragma unroll
    for (int i = 0; i < 8; ++i) {
        ushort_t u = emb[(size_t)(lane * 8 + i) * 2];
        int a = u & 0x7FFF;
        int e = (u >> 7) & 0xFF;
        if (a == 0 || (e >= 111 && e <= 143)) cnt++;
    }
    cnt += __shfl_xor(cnt, 1);  cnt += __shfl_xor(cnt, 2);  cnt += __shfl_xor(cnt, 4);
    cnt += __shfl_xor(cnt, 8);  cnt += __shfl_xor(cnt, 16); cnt += __shfl_xor(cnt, 32);
    return cnt < 460;
}

#define LDA 520   // 260 dw, %32=4: uniform bank spread for b128 row reads
#define LDP 264

// ---------------------------------------------------------------------------
// Dtype probe kernel: flag=1 => bf16 data, flag=0 => fp32. (fallback tiers)
// ---------------------------------------------------------------------------
__global__ void detect_kernel(const ushort_t* __restrict__ emb, int* __restrict__ flag)
{
    int lane = threadIdx.x;
    int cnt = 0;
    #pragma unroll
    for (int i = 0; i < 8; ++i) {
        ushort_t u = emb[(size_t)(lane * 8 + i) * 2];
        int a = u & 0x7FFF;
        int e = (u >> 7) & 0xFF;
        if (a == 0 || (e >= 111 && e <= 143)) cnt++;
    }
    cnt += __shfl_xor(cnt, 1);  cnt += __shfl_xor(cnt, 2);  cnt += __shfl_xor(cnt, 4);
    cnt += __shfl_xor(cnt, 8);  cnt += __shfl_xor(cnt, 16); cnt += __shfl_xor(cnt, 32);
    if (lane == 0) *flag = (cnt >= 460) ? 1 : 0;
}

// ---------------------------------------------------------------------------
// Prep (fallback tiers only): convert Wqk, Wv + biases to bf16 in ws.
// ---------------------------------------------------------------------------
__global__ __launch_bounds__(256)
void prep_kernel(const int* __restrict__ flag,
                 const void* __restrict__ Wqk, const void* __restrict__ bqk,
                 const void* __restrict__ Wv,  const void* __restrict__ bv,
                 ushort_t* __restrict__ Wqkb, ushort_t* __restrict__ bqkb,
                 ushort_t* __restrict__ Wvb,  ushort_t* __restrict__ bvb)
{
    const bool f32 = (*flag == 0);
    size_t gid = (size_t)blockIdx.x * 256 + threadIdx.x;   // 32768 threads
    size_t base = gid * 8;                                  // 262144 = 512*512
    *(bf16x8*)&Wqkb[base] = load8(Wqk, base, f32);
    *(bf16x8*)&Wvb[base]  = load8(Wv,  base, f32);
    if (gid < 64) {
        *(bf16x8*)&bqkb[base] = load8(bqk, base, f32);
        *(bf16x8*)&bvb[base]  = load8(bv,  base, f32);
    }
}

// ---------------------------------------------------------------------------
// R19 top-tier fused projection: Q[32 rows] = emb@Wqk^T+bqk AND embT columns.
// Inline dtype probe; weights read directly (fp32 or bf16). 256 blocks x 512.
// ---------------------------------------------------------------------------
__global__ __launch_bounds__(512)
void projqT2_kernel(const void* __restrict__ emb,
                    const void* __restrict__ Wqk, const void* __restrict__ bqk,
                    ushort_t* __restrict__ C, ushort_t* __restrict__ embT)
{
    __shared__ ushort_t Alds[32][LDA];   // 33,280 B
    const bool f32 = probe_f32((const ushort_t*)emb);
    const int tid  = threadIdx.x;
    const int wave = tid >> 6;
    const int lane = tid & 63;
    const int quad = lane >> 4;
    const int col  = lane & 15;
    const int mblk = blockIdx.x * 32;

    #pragma unroll
    for (int i = 0; i < 4; ++i) {
        int chunk = i * 512 + tid;
        int row = chunk >> 6;
        int k8  = (chunk & 63) * 8;
        *(bf16x8*)&Alds[row][k8] = load8(emb, (size_t)(mblk + row) * 512 + k8, f32);
    }
    __syncthreads();

    // ---- transpose store: thread t owns dim t, 32 tokens (64 B) ----
    {
        ushort_t buf[32];
        #pragma unroll
        for (int r = 0; r < 32; ++r) buf[r] = Alds[r][tid];
        ushort_t* dst = embT + (size_t)tid * NTOK + mblk;
        #pragma unroll
        for (int i = 0; i < 4; ++i)
            *(uint4*)(dst + i * 8) = *(uint4*)&buf[i * 8];
    }

    // ---- Q projection (32 rows x this wave's 64 cols) ----
    f32x4 acc[2][4];
    #pragma unroll
    for (int r = 0; r < 2; ++r)
        #pragma unroll
        for (int c = 0; c < 4; ++c) acc[r][c] = (f32x4){0.f, 0.f, 0.f, 0.f};

    const int wcol = wave * 64;
    #pragma unroll
    for (int kk = 0; kk < 16; ++kk) {
        bf16x8 a0 = *(const bf16x8*)&Alds[col][kk * 32 + quad * 8];
        bf16x8 a1 = *(const bf16x8*)&Alds[16 + col][kk * 32 + quad * 8];
        #pragma unroll
        for (int c = 0; c < 4; ++c) {
            bf16x8 b = load8(Wqk, (size_t)(wcol + c * 16 + col) * 512
                                   + kk * 32 + quad * 8, f32);
            acc[0][c] = mfma16(a0, b, acc[0][c]);
            acc[1][c] = mfma16(a1, b, acc[1][c]);
        }
    }

    #pragma unroll
    for (int r = 0; r < 2; ++r)
        #pragma unroll
        for (int c = 0; c < 4; ++c)
            #pragma unroll
            for (int g = 0; g < 4; ++g) {
                int m = mblk + r * 16 + quad * 4 + g;
                int n = wcol + c * 16 + col;
                C[(size_t)m * DIM + n] = f2bf(acc[r][c][g] + loadS(bqk, n, f32));
            }
}

// ---------------------------------------------------------------------------
// attn128 (R17-proven core + R18 XCD-aligned remap, byte-identical to R18):
// 256 blocks = 64 q-tiles (Tq=128) x 4 key-quarters, 512 thr = 8 waves.
// ---------------------------------------------------------------------------
#define QT2  128
#define KT2  64
#define NIT2 32

__global__ __launch_bounds__(512, 2)
void attn128_kernel(const ushort_t* __restrict__ Q, const ushort_t* __restrict__ embT,
                    ushort_t* __restrict__ P, float* __restrict__ lsumA)
{
    __shared__ ushort_t Klds[2][KT2 * DIM];   // 131,072 B
    __shared__ ushort_t Plds[QT2 * KT2];      //  16,384 B (147,456 total)

    const int tid  = threadIdx.x;
    const int wave = tid >> 6;
    const int lane = tid & 63;
    const int quad = lane >> 4;
    const int col  = lane & 15;
    const int bid  = blockIdx.x;
    const int ks   = (bid & 7) >> 1;                      // XCD pair -> quarter
    const int qt   = ((bid >> 3) << 1) | (bid & 1);       // 0..63 bijective
    const int q0   = qt * QT2;
    const int kbase = ks * (NTOK / 4);
    ushort_t* Ps = P + (size_t)ks * NTOK * DIM;

    // Swizzle constants (K reads row=kt*16+col; P reads row=rt*16+col).
    const int s3 = col & 7;
    const int qo = (quad ^ (s3 & 3)) << 4;    // byte bits 4-5
    const int kx = (s3 >> 2) << 6;            // byte bit 6

    // ---- Q fragments: wave owns rows [q0+16w, +16), full K=512 (64 VGPR) ----
    bf16x8 qf[16];
    {
        const ushort_t* qrow = Q + (size_t)(q0 + wave * 16 + col) * DIM + quad * 8;
        #pragma unroll
        for (int kk = 0; kk < 16; ++kk)
            qf[kk] = *(const bf16x8*)(qrow + kk * 32);
    }

    // K-read byte bases per key-tile
    int rbk[4];
    #pragma unroll
    for (int kt = 0; kt < 4; ++kt)
        rbk[kt] = (((kt * 16 + col) << 10) | qo) ^ kx;

    const int pwrow = wave * 16 + quad * 4;          // P-write row base (+g)
    const int pb    = ((col << 7) | qo) ^ kx;        // PV-read byte base

    // ---- stage K(0) into buf 0 ----
    {
        const size_t gb = (size_t)kbase * DIM;
        #pragma unroll
        for (int i = 0; i < 8; ++i) {
            const int r = wave * 8 + i;
            gload_lds16(Q + gb + (size_t)r * DIM + ((lane ^ (r & 7)) << 3),
                        &Klds[0][r * DIM]);
        }
    }

    f32x4 accO[8][4];
    #pragma unroll
    for (int r = 0; r < 8; ++r)
        #pragma unroll
        for (int c = 0; c < 4; ++c) accO[r][c] = (f32x4){0.f, 0.f, 0.f, 0.f};
    float lsum[4] = {0.f, 0.f, 0.f, 0.f};

    const float sc = 0.04419417382415922f * 1.4426950408889634f;  // 1/sqrt(512)*log2e
    const int wd = wave * 64;

    for (int it = 0; it < NIT2; ++it) {
        const int cur = it & 1;
        const char* Kc = (const char*)&Klds[cur][0];
        const int j0 = kbase + it * KT2;

        // ---- prefetch K(t+1); counted vmcnt waits only for K(t)'s loads ----
        if (it + 1 < NIT2) {
            const size_t gb = (size_t)(j0 + KT2) * DIM;
            ushort_t* dst = &Klds[cur ^ 1][0];
            #pragma unroll
            for (int i = 0; i < 8; ++i) {
                const int r = wave * 8 + i;
                gload_lds16(Q + gb + (size_t)r * DIM + ((lane ^ (r & 7)) << 3),
                            dst + r * DIM);
            }
            asm volatile("s_waitcnt vmcnt(8)" ::: "memory");
        } else {
            asm volatile("s_waitcnt vmcnt(0)" ::: "memory");
        }
        // Top barrier: K(t) staged AND all waves done with P(t-1)
        __builtin_amdgcn_s_barrier();

        // ---- S = Q(wave's 16 rows) @ K(all 64 keys)^T, A from registers ----
        f32x4 accS[4];
        #pragma unroll
        for (int kt = 0; kt < 4; ++kt) accS[kt] = (f32x4){0.f, 0.f, 0.f, 0.f};
        __builtin_amdgcn_s_setprio(1);
        #pragma unroll
        for (int kk = 0; kk < 16; ++kk)
            #pragma unroll
            for (int kt = 0; kt < 4; ++kt) {
                bf16x8 kb = *(const bf16x8*)(Kc + (rbk[kt] ^ (kk << 6)));
                accS[kt] = mfma16(qf[kk], kb, accS[kt]);
            }
        __builtin_amdgcn_s_setprio(0);

        // ---- P = exp2(S*sc) -> swizzled Plds; row sums (rows wave-owned) ----
        #pragma unroll
        for (int kt = 0; kt < 4; ++kt)
            #pragma unroll
            for (int g = 0; g < 4; ++g) {
                float p = exp2f(fminf(accS[kt][g] * sc, 126.0f));
                lsum[g] += p;
                const int prow = pwrow + g;
                Plds[(prow << 6) | ((kt * 16 + col) ^ ((prow & 7) << 3))] = f2bf(p);
            }

        // ---- vb kslot 0 (global; latency hidden under exp + barrier) ----
        const ushort_t* eb = embT + (size_t)(wd + col) * NTOK + j0 + quad * 8;
        bf16x8 vb0[4];
        #pragma unroll
        for (int dt = 0; dt < 4; ++dt)
            vb0[dt] = *(const bf16x8*)(eb + (size_t)(dt * 16) * NTOK);

        // ---- B1: P visible (LDS only; K-prefetch stays in flight) ----
        asm volatile("s_waitcnt lgkmcnt(0)" ::: "memory");
        __builtin_amdgcn_s_barrier();

        // ---- PV kslot 0: O += P[:, 0:32] @ embT[:, 0:32]^T ----
        __builtin_amdgcn_s_setprio(1);
        #pragma unroll
        for (int rt = 0; rt < 8; ++rt) {
            bf16x8 pa = *(const bf16x8*)((const char*)Plds + (rt * 2048 + pb));
            #pragma unroll
            for (int dt = 0; dt < 4; ++dt)
                accO[rt][dt] = mfma16(pa, vb0[dt], accO[rt][dt]);
        }
        __builtin_amdgcn_s_setprio(0);

        // ---- vb kslot 1 + PV kslot 1 ----
        bf16x8 vb1[4];
        #pragma unroll
        for (int dt = 0; dt < 4; ++dt)
            vb1[dt] = *(const bf16x8*)(eb + (size_t)(dt * 16) * NTOK + 32);

        __builtin_amdgcn_s_setprio(1);
        #pragma unroll
        for (int rt = 0; rt < 8; ++rt) {
            bf16x8 pa = *(const bf16x8*)((const char*)Plds + (rt * 2048 + (pb ^ 64)));
            #pragma unroll
            for (int dt = 0; dt < 4; ++dt)
                accO[rt][dt] = mfma16(pa, vb1[dt], accO[rt][dt]);
        }
        __builtin_amdgcn_s_setprio(0);
        // No end barrier: next iter's top barrier fences P(t) vs P(t+1).
    }

    // ---- row sums: reduce over col lanes (keys); rows wave-owned ----
    #pragma unroll
    for (int g = 0; g < 4; ++g) {
        float s = lsum[g];
        s += __shfl_xor(s, 1);
        s += __shfl_xor(s, 2);
        s += __shfl_xor(s, 4);
        s += __shfl_xor(s, 8);
        if (col == 0)
            lsumA[(size_t)ks * NTOK + q0 + pwrow + g] = s;
    }

    // ---- store O partial (pre-normalization) ----
    #pragma unroll
    for (int rt = 0; rt < 8; ++rt)
        #pragma unroll
        for (int dt = 0; dt < 4; ++dt)
            #pragma unroll
            for (int g = 0; g < 4; ++g)
                Ps[(size_t)(q0 + rt * 16 + quad * 4 + g) * DIM + wd + dt * 16 + col]
                    = f2bf(accO[rt][dt][g]);
}

// ---------------------------------------------------------------------------
// R19 finalize: T = (P0..P3)/(l0..l3), out = T @ Wv^T + bv. Inline probe,
// direct weight reads. 32-row tiles x 256 blocks.
// ---------------------------------------------------------------------------
__global__ __launch_bounds__(512)
void finalize42_kernel(const void* __restrict__ emb,
                       const ushort_t* __restrict__ P, const float* __restrict__ lsumA,
                       const void* __restrict__ Wv, const void* __restrict__ bv,
                       void* __restrict__ Out)
{
    __shared__ ushort_t Alds[32][LDA];
    const bool f32 = probe_f32((const ushort_t*)emb);
    const int tid  = threadIdx.x;
    const int wave = tid >> 6;
    const int lane = tid & 63;
    const int quad = lane >> 4;
    const int col  = lane & 15;
    const int mblk = blockIdx.x * 32;
    const size_t PSZ = (size_t)NTOK * DIM;

    #pragma unroll
    for (int i = 0; i < 4; ++i) {
        int chunk = i * 512 + tid;
        int row = chunk >> 6;
        int k8  = (chunk & 63) * 8;
        int m   = mblk + row;
        float rv = 1.0f / (lsumA[m] + lsumA[NTOK + m]
                         + lsumA[2 * NTOK + m] + lsumA[3 * NTOK + m]);
        size_t off = (size_t)m * 512 + k8;
        bf16x8 v0 = *(const bf16x8*)&P[off];
        bf16x8 v1 = *(const bf16x8*)&P[PSZ + off];
        bf16x8 v2 = *(const bf16x8*)&P[2 * PSZ + off];
        bf16x8 v3 = *(const bf16x8*)&P[3 * PSZ + off];
        bf16x8 t;
        #pragma unroll
        for (int j = 0; j < 8; ++j)
            t[j] = f2bfh(((float)v0[j] + (float)v1[j] + (float)v2[j] + (float)v3[j]) * rv);
        *(bf16x8*)&Alds[row][k8] = t;
    }
    __syncthreads();

    f32x4 acc[2][4];
    #pragma unroll
    for (int r = 0; r < 2; ++r)
        #pragma unroll
        for (int c = 0; c < 4; ++c) acc[r][c] = (f32x4){0.f, 0.f, 0.f, 0.f};

    const int wcol = wave * 64;
    #pragma unroll
    for (int kk = 0; kk < 16; ++kk) {
        bf16x8 a0 = *(const bf16x8*)&Alds[col][kk * 32 + quad * 8];
        bf16x8 a1 = *(const bf16x8*)&Alds[16 + col][kk * 32 + quad * 8];
        #pragma unroll
        for (int c = 0; c < 4; ++c) {
            bf16x8 b = load8(Wv, (size_t)(wcol + c * 16 + col) * 512
                                  + kk * 32 + quad * 8, f32);
            acc[0][c] = mfma16(a0, b, acc[0][c]);
            acc[1][c] = mfma16(a1, b, acc[1][c]);
        }
    }

    #pragma unroll
    for (int r = 0; r < 2; ++r)
        #pragma unroll
        for (int c = 0; c < 4; ++c)
            #pragma unroll
            for (int g = 0; g < 4; ++g) {
                int m = mblk + r * 16 + quad * 4 + g;
                int n = wcol + c * 16 + col;
                float v = acc[r][c][g] + loadS(bv, n, f32);
                if (f32) ((float*)Out)[(size_t)m * DIM + n] = v;
                else     ((ushort_t*)Out)[(size_t)m * DIM + n] = f2bf(v);
            }
}

// ---------------------------------------------------------------------------
// R13-proven attn64 + finalize (fallback for mid-size workspace).
// ---------------------------------------------------------------------------
__global__ __launch_bounds__(1024)
void attn64_kernel(const ushort_t* __restrict__ Q, const ushort_t* __restrict__ embT,
                   ushort_t* __restrict__ P0, ushort_t* __restrict__ P1,
                   float* __restrict__ lsumA)
{
    __shared__ ushort_t Qlds[64][LDA];
    __shared__ ushort_t Plds[2][64][LDP];
    __shared__ float    Lp[16][64];

    const int tid  = threadIdx.x;
    const int wave = tid >> 6;
    const int lane = tid & 63;
    const int quad = lane >> 4;
    const int col  = lane & 15;
    const int qt   = blockIdx.x & 127;
    const int ks   = blockIdx.x >> 7;
    const int q0   = qt * 64;
    const int kbase = ks * 4096;
    ushort_t* Ps = ks ? P1 : P0;

    #pragma unroll
    for (int i = 0; i < 4; ++i) {
        int chunk = i * 1024 + tid;
        int row = chunk >> 6;
        int k8  = (chunk & 63) * 8;
        *(bf16x8*)&Qlds[row][k8] = *(const bf16x8*)&Q[(size_t)(q0 + row) * 512 + k8];
    }
    __syncthreads();

    f32x4 accO[4][2];
    #pragma unroll
    for (int r = 0; r < 4; ++r)
        #pragma unroll
        for (int c = 0; c < 2; ++c) accO[r][c] = (f32x4){0.f, 0.f, 0.f, 0.f};

    float lsum[4][4];
    #pragma unroll
    for (int r = 0; r < 4; ++r)
        #pragma unroll
        for (int g = 0; g < 4; ++g) lsum[r][g] = 0.f;

    const float sc = 0.04419417382415922f * 1.4426950408889634f;
    const int wd = wave * 32;

    for (int it = 0; it < 16; ++it) {
        const int j0  = kbase + it * 256;
        const int buf = it & 1;

        f32x4 accS[4];
        #pragma unroll
        for (int r = 0; r < 4; ++r) accS[r] = (f32x4){0.f, 0.f, 0.f, 0.f};
        const size_t keyrow = (size_t)(j0 + wave * 16 + col) * 512;
        #pragma unroll
        for (int h = 0; h < 2; ++h) {
            bf16x8 kb[8];
            #pragma unroll
            for (int kk = 0; kk < 8; ++kk)
                kb[kk] = *(const bf16x8*)&Q[keyrow + (h * 8 + kk) * 32 + quad * 8];
            #pragma unroll
            for (int kk = 0; kk < 8; ++kk) {
                const int cofs = (h * 8 + kk) * 32 + quad * 8;
                #pragma unroll
                for (int r = 0; r < 4; ++r) {
                    bf16x8 a = *(const bf16x8*)&Qlds[r * 16 + col][cofs];
                    accS[r] = mfma16(a, kb[kk], accS[r]);
                }
            }
        }

        bf16x8 vbA[8];
        #pragma unroll
        for (int kk = 0; kk < 4; ++kk)
            #pragma unroll
            for (int c = 0; c < 2; ++c)
                vbA[kk * 2 + c] = *(const bf16x8*)&embT[
                    (size_t)(wd + c * 16 + col) * NTOK + j0 + kk * 32 + quad * 8];

        #pragma unroll
        for (int r = 0; r < 4; ++r)
            #pragma unroll
            for (int g = 0; g < 4; ++g) {
                float p = exp2f(fminf(accS[r][g] * sc, 126.0f));
                lsum[r][g] += p;
                Plds[buf][r * 16 + quad * 4 + g][wave * 16 + col] = f2bf(p);
            }

        bf16x8 vbB[8];
        #pragma unroll
        for (int kk = 0; kk < 4; ++kk)
            #pragma unroll
            for (int c = 0; c < 2; ++c)
                vbB[kk * 2 + c] = *(const bf16x8*)&embT[
                    (size_t)(wd + c * 16 + col) * NTOK + j0 + (4 + kk) * 32 + quad * 8];

        __syncthreads();

        #pragma unroll
        for (int kk = 0; kk < 4; ++kk) {
            #pragma unroll
            for (int r = 0; r < 4; ++r) {
                bf16x8 a = *(const bf16x8*)&Plds[buf][r * 16 + col][kk * 32 + quad * 8];
                #pragma unroll
                for (int c = 0; c < 2; ++c)
                    accO[r][c] = mfma16(a, vbA[kk * 2 + c], accO[r][c]);
            }
        }
        #pragma unroll
        for (int kk = 0; kk < 4; ++kk) {
            #pragma unroll
            for (int r = 0; r < 4; ++r) {
                bf16x8 a = *(const bf16x8*)&Plds[buf][r * 16 + col][(4 + kk) * 32 + quad * 8];
                #pragma unroll
                for (int c = 0; c < 2; ++c)
                    accO[r][c] = mfma16(a, vbB[kk * 2 + c], accO[r][c]);
            }
        }
    }

    #pragma unroll
    for (int r = 0; r < 4; ++r)
        #pragma unroll
        for (int g = 0; g < 4; ++g) {
            float s = lsum[r][g];
            s += __shfl_xor(s, 1);
            s += __shfl_xor(s, 2);
            s += __shfl_xor(s, 4);
            s += __shfl_xor(s, 8);
            if (col == 0)
                Lp[wave][r * 16 + quad * 4 + g] = s;
        }
    __syncthreads();
    if (tid < 64) {
        float t = 0.f;
        #pragma unroll
        for (int w = 0; w < 16; ++w) t += Lp[w][tid];
        lsumA[(size_t)ks * NTOK + q0 + tid] = t;
    }

    #pragma unroll
    for (int r = 0; r < 4; ++r)
        #pragma unroll
        for (int c = 0; c < 2; ++c)
            #pragma unroll
            for (int g = 0; g < 4; ++g)
                Ps[(size_t)(q0 + r * 16 + quad * 4 + g) * DIM + wd + c * 16 + col]
                    = f2bf(accO[r][c][g]);
}

__global__ __launch_bounds__(512)
void finalize_kernel(const int* __restrict__ flag,
                     const ushort_t* __restrict__ P0, const ushort_t* __restrict__ P1,
                     const float* __restrict__ lsumA,
                     const ushort_t* __restrict__ Wb, const ushort_t* __restrict__ bb,
                     void* __restrict__ Out)
{
    __shared__ ushort_t Alds[64][LDA];
    const bool f32 = (*flag == 0);
    const int tid  = threadIdx.x;
    const int wave = tid >> 6;
    const int lane = tid & 63;
    const int quad = lane >> 4;
    const int col  = lane & 15;
    const int mblk = blockIdx.x * 64;

    #pragma unroll
    for (int i = 0; i < 8; ++i) {
        int chunk = i * 512 + tid;
        int row = chunk >> 6;
        int k8  = (chunk & 63) * 8;
        int m   = mblk + row;
        float rv = 1.0f / (lsumA[m] + lsumA[NTOK + m]);
        bf16x8 v0 = *(const bf16x8*)&P0[(size_t)m * 512 + k8];
        bf16x8 v1 = *(const bf16x8*)&P1[(size_t)m * 512 + k8];
        bf16x8 t;
        #pragma unroll
        for (int j = 0; j < 8; ++j) t[j] = f2bfh(((float)v0[j] + (float)v1[j]) * rv);
        *(bf16x8*)&Alds[row][k8] = t;
    }
    __syncthreads();

    f32x4 acc[4][4];
    #pragma unroll
    for (int r = 0; r < 4; ++r)
        #pragma unroll
        for (int c = 0; c < 4; ++c) acc[r][c] = (f32x4){0.f, 0.f, 0.f, 0.f};

    const int wcol = wave * 64;
    #pragma unroll
    for (int kk = 0; kk < 16; ++kk) {
        bf16x8 a[4];
        #pragma unroll
        for (int r = 0; r < 4; ++r)
            a[r] = *(const bf16x8*)&Alds[r * 16 + col][kk * 32 + quad * 8];
        #pragma unroll
        for (int c = 0; c < 4; ++c) {
            bf16x8 b = *(const bf16x8*)&Wb[(size_t)(wcol + c * 16 + col) * 512
                                           + kk * 32 + quad * 8];
            #pragma unroll
            for (int r = 0; r < 4; ++r)
                acc[r][c] = mfma16(a[r], b, acc[r][c]);
        }
    }

    #pragma unroll
    for (int r = 0; r < 4; ++r)
        #pragma unroll
        for (int c = 0; c < 4; ++c)
            #pragma unroll
            for (int g = 0; g < 4; ++g) {
                int m = mblk + r * 16 + quad * 4 + g;
                int n = wcol + c * 16 + col;
                float v = acc[r][c][g] + bf2f(bb[n]);
                if (f32) ((float*)Out)[(size_t)m * DIM + n] = v;
                else     ((ushort_t*)Out)[(size_t)m * DIM + n] = f2bf(v);
            }
}

// ---------------------------------------------------------------------------
// Fallback kernels (R13-proven) for smaller workspaces.
// ---------------------------------------------------------------------------
__global__ __launch_bounds__(256)
void transpose_kernel(const int* __restrict__ flag, const void* __restrict__ emb,
                      ushort_t* __restrict__ embT)
{
    __shared__ float tile[64][65];
    const bool f32 = (*flag == 0);
    const int t  = threadIdx.x;
    const int j0 = blockIdx.x * 64;
    const int d0 = blockIdx.y * 64;
    {
        int r = t >> 2, cs = (t & 3) * 16;
        if (f32) {
            const float* src = (const float*)emb + (size_t)(j0 + r) * DIM + d0 + cs;
            #pragma unroll
            for (int i = 0; i < 16; i += 4) {
                float4 v = *(const float4*)(src + i);
                tile[r][cs + i]     = v.x;
                tile[r][cs + i + 1] = v.y;
                tile[r][cs + i + 2] = v.z;
                tile[r][cs + i + 3] = v.w;
            }
        } else {
            const ushort_t* src = (const ushort_t*)emb + (size_t)(j0 + r) * DIM + d0 + cs;
            #pragma unroll
            for (int i = 0; i < 16; ++i) tile[r][cs + i] = bf2f(src[i]);
        }
    }
    __syncthreads();
    {
        int d = t >> 2, js = (t & 3) * 16;
        ushort_t buf[16];
        #pragma unroll
        for (int i = 0; i < 16; ++i) buf[i] = f2bf(tile[js + i][d]);
        ushort_t* dst = embT + (size_t)(d0 + d) * NTOK + j0 + js;
        *(uint4*)dst       = *(uint4*)&buf[0];
        *(uint4*)(dst + 8) = *(uint4*)&buf[8];
    }
}

__global__ __launch_bounds__(512)
void projq_kernel(const int* __restrict__ flag, const void* __restrict__ emb,
                  const void* __restrict__ W, const void* __restrict__ bias,
                  ushort_t* __restrict__ C)
{
    __shared__ ushort_t Alds[32][LDA];
    const bool f32 = (*flag == 0);
    const int tid  = threadIdx.x;
    const int wave = tid >> 6;
    const int lane = tid & 63;
    const int quad = lane >> 4;
    const int col  = lane & 15;
    const int mblk = blockIdx.x * 32;

    #pragma unroll
    for (int i = 0; i < 4; ++i) {
        int chunk = i * 512 + tid;
        int row = chunk >> 6;
        int k8  = (chunk & 63) * 8;
        *(bf16x8*)&Alds[row][k8] = load8(emb, (size_t)(mblk + row) * 512 + k8, f32);
    }
    __syncthreads();

    f32x4 acc[2][4];
    #pragma unroll
    for (int r = 0; r < 2; ++r)
        #pragma unroll
        for (int c = 0; c < 4; ++c) acc[r][c] = (f32x4){0.f, 0.f, 0.f, 0.f};

    const int wcol = wave * 64;
    #pragma unroll
    for (int kk = 0; kk < 16; ++kk) {
        bf16x8 a0 = *(const bf16x8*)&Alds[col][kk * 32 + quad * 8];
        bf16x8 a1 = *(const bf16x8*)&Alds[16 + col][kk * 32 + quad * 8];
        #pragma unroll
        for (int c = 0; c < 4; ++c) {
            bf16x8 b = load8(W, (size_t)(wcol + c * 16 + col) * 512 + kk * 32 + quad * 8, f32);
            acc[0][c] = mfma16(a0, b, acc[0][c]);
            acc[1][c] = mfma16(a1, b, acc[1][c]);
        }
    }

    #pragma unroll
    for (int r = 0; r < 2; ++r)
        #pragma unroll
        for (int c = 0; c < 4; ++c)
            #pragma unroll
            for (int g = 0; g < 4; ++g) {
                int m = mblk + r * 16 + quad * 4 + g;
                int n = wcol + c * 16 + col;
                C[(size_t)m * DIM + n] = f2bf(acc[r][c][g] + loadS(bias, n, f32));
            }
}

template <int VT>
__global__ __launch_bounds__(1024)
void attn_fused_kernel(const int* __restrict__ flag, const ushort_t* __restrict__ Q,
                       const void* __restrict__ embOrT, const void* __restrict__ Wv,
                       const void* __restrict__ bv, void* __restrict__ Out)
{
    __shared__ ushort_t Qlds[32][LDA];
    __shared__ ushort_t Plds[2][32][LDP];
    __shared__ float    Lpart[16][32];

    const bool f32 = (*flag == 0);
    const int tid  = threadIdx.x;
    const int wave = tid >> 6;
    const int lane = tid & 63;
    const int quad = lane >> 4;
    const int col  = lane & 15;
    const int q0   = blockIdx.x * 32;

    #pragma unroll
    for (int i = 0; i < 2; ++i) {
        int chunk = i * 1024 + tid;
        int row = chunk >> 6;
        int k8  = (chunk & 63) * 8;
        *(bf16x8*)&Qlds[row][k8] = *(const bf16x8*)&Q[(size_t)(q0 + row) * 512 + k8];
    }
    __syncthreads();

    f32x4 accO[2][2];
    #pragma unroll
    for (int r = 0; r < 2; ++r)
        #pragma unroll
        for (int c = 0; c < 2; ++c) accO[r][c] = (f32x4){0.f, 0.f, 0.f, 0.f};

    float lsum[2][4];
    #pragma unroll
    for (int r = 0; r < 2; ++r)
        #pragma unroll
        for (int g = 0; g < 4; ++g) lsum[r][g] = 0.f;

    const float sc = 0.04419417382415922f * 1.4426950408889634f;
    const int wOcol = wave * 32;

    for (int it = 0; it < 32; ++it) {
        const int j0  = it * 256;
        const int buf = it & 1;

        bf16x8 kb[16];
        const size_t keyrow = (size_t)(j0 + wave * 16 + col) * 512;
        #pragma unroll
        for (int kk = 0; kk < 16; ++kk)
            kb[kk] = *(const bf16x8*)&Q[keyrow + kk * 32 + quad * 8];

        f32x4 accS[2];
        accS[0] = (f32x4){0.f, 0.f, 0.f, 0.f};
        accS[1] = (f32x4){0.f, 0.f, 0.f, 0.f};
        #pragma unroll
        for (int kk = 0; kk < 16; ++kk) {
            bf16x8 a0 = *(const bf16x8*)&Qlds[col][kk * 32 + quad * 8];
            bf16x8 a1 = *(const bf16x8*)&Qlds[16 + col][kk * 32 + quad * 8];
            accS[0] = mfma16(a0, kb[kk], accS[0]);
            accS[1] = mfma16(a1, kb[kk], accS[1]);
        }

        bf16x8 vb[16];
        #pragma unroll
        for (int kk = 0; kk < 8; ++kk)
            #pragma unroll
            for (int c = 0; c < 2; ++c) {
                if (VT) {
                    vb[kk * 2 + c] = *(const bf16x8*)((const ushort_t*)embOrT
                        + (size_t)(wOcol + c * 16 + col) * NTOK + j0 + kk * 32 + quad * 8);
                } else {
                    size_t base = (size_t)(j0 + kk * 32 + quad * 8) * 512 + (wOcol + c * 16 + col);
                    bf16x8 b;
                    if (f32) {
                        const float* bp = (const float*)embOrT + base;
                        #pragma unroll
                        for (int j = 0; j < 8; ++j) b[j] = f2bfh(bp[(size_t)j * 512]);
                    } else {
                        const __bf16* bp = (const __bf16*)embOrT + base;
                        #pragma unroll
                        for (int j = 0; j < 8; ++j) b[j] = bp[(size_t)j * 512];
                    }
                    vb[kk * 2 + c] = b;
                }
            }

        #pragma unroll
        for (int r = 0; r < 2; ++r)
            #pragma unroll
            for (int g = 0; g < 4; ++g) {
                float p = exp2f(fminf(accS[r][g] * sc, 126.0f));
                lsum[r][g] += p;
                Plds[buf][r * 16 + quad * 4 + g][wave * 16 + col] = f2bf(p);
            }

        __syncthreads();

        #pragma unroll
        for (int kk = 0; kk < 8; ++kk) {
            bf16x8 a0 = *(const bf16x8*)&Plds[buf][col][kk * 32 + quad * 8];
            bf16x8 a1 = *(const bf16x8*)&Plds[buf][16 + col][kk * 32 + quad * 8];
            #pragma unroll
            for (int c = 0; c < 2; ++c) {
                accO[0][c] = mfma16(a0, vb[kk * 2 + c], accO[0][c]);
                accO[1][c] = mfma16(a1, vb[kk * 2 + c], accO[1][c]);
            }
        }
    }

    #pragma unroll
    for (int r = 0; r < 2; ++r)
        #pragma unroll
        for (int g = 0; g < 4; ++g) {
            float s = lsum[r][g];
            s += __shfl_xor(s, 1);
            s += __shfl_xor(s, 2);
            s += __shfl_xor(s, 4);
            s += __shfl_xor(s, 8);
            lsum[r][g] = s;
        }
    if (col == 0) {
        #pragma unroll
        for (int r = 0; r < 2; ++r)
            #pragma unroll
            for (int g = 0; g < 4; ++g)
                Lpart[wave][r * 16 + quad * 4 + g] = lsum[r][g];
    }
    __syncthreads();

    #pragma unroll
    for (int r = 0; r < 2; ++r) {
        float rinv[4];
        #pragma unroll
        for (int g = 0; g < 4; ++g) {
            float t = 0.f;
            #pragma unroll
            for (int w = 0; w < 16; ++w) t += Lpart[w][r * 16 + quad * 4 + g];
            rinv[g] = 1.0f / t;
        }
        #pragma unroll
        for (int c = 0; c < 2; ++c)
            #pragma unroll
            for (int g = 0; g < 4; ++g)
                Qlds[r * 16 + quad * 4 + g][wOcol + c * 16 + col] = f2bf(accO[r][c][g] * rinv[g]);
    }
    __syncthreads();

    f32x4 acc2[2][2];
    #pragma unroll
    for (int r = 0; r < 2; ++r)
        #pragma unroll
        for (int c = 0; c < 2; ++c) acc2[r][c] = (f32x4){0.f, 0.f, 0.f, 0.f};

    #pragma unroll
    for (int kk = 0; kk < 16; ++kk) {
        bf16x8 a0 = *(const bf16x8*)&Qlds[col][kk * 32 + quad * 8];
        bf16x8 a1 = *(const bf16x8*)&Qlds[16 + col][kk * 32 + quad * 8];
        #pragma unroll
        for (int c = 0; c < 2; ++c) {
            bf16x8 b = load8(Wv, (size_t)(wOcol + c * 16 + col) * 512 + kk * 32 + quad * 8, f32);
            acc2[0][c] = mfma16(a0, b, acc2[0][c]);
            acc2[1][c] = mfma16(a1, b, acc2[1][c]);
        }
    }

    #pragma unroll
    for (int r = 0; r < 2; ++r)
        #pragma unroll
        for (int c = 0; c < 2; ++c)
            #pragma unroll
            for (int g = 0; g < 4; ++g) {
                int m = q0 + r * 16 + quad * 4 + g;
                int n = wOcol + c * 16 + col;
                float v = acc2[r][c][g] + loadS(bv, n, f32);
                if (f32) ((float*)Out)[(size_t)m * DIM + n] = v;
                else     ((ushort_t*)Out)[(size_t)m * DIM + n] = f2bf(v);
            }
}

extern "C" void kernel_launch(void* const* d_in, const int* in_sizes, int n_in,
                              void* d_out, int out_size, void* d_ws, size_t ws_size,
                              hipStream_t stream)
{
    const void* emb = d_in[0];
    const void* Wqk = d_in[1];
    const void* bqk = d_in[2];
    const void* Wv  = d_in[3];
    const void* bv  = d_in[4];

    char* W = (char*)d_ws;

    // R19 top-tier layout: lsum4 (128KB, 64B-aligned base) | embT | Qws | P[4]
    const size_t needC = 64 + 4 * (size_t)NTOK * 4
                       + 6 * (size_t)NTOK * DIM * 2;                  // ~48.3 MB
    // Old (R14) layout for mid tier
    const size_t needA = 64 + 65536 + 2 * (size_t)DIM * DIM * 2 + 2 * DIM * 2
                       + 4 * (size_t)NTOK * DIM * 2;                  // ~33.1 MB
    const size_t needB = 64 + 2 * (size_t)NTOK * DIM * 2;             // 16.03 MB

    if (ws_size >= needC) {
        float*    lsum4 = (float*)(W + 64);                          // 128 KB
        ushort_t* embT  = (ushort_t*)(W + 64 + 4 * (size_t)NTOK * 4);// 8 MB
        ushort_t* Qws   = embT + (size_t)DIM * NTOK;                 // 8 MB
        ushort_t* P4    = Qws + (size_t)DIM * NTOK;                  // 4 x 8 MB

        projqT2_kernel<<<dim3(NTOK / 32), dim3(512), 0, stream>>>(emb, Wqk, bqk,
                                                                  Qws, embT);
        attn128_kernel<<<dim3(256), dim3(512), 0, stream>>>(Qws, embT, P4, lsum4);
        finalize42_kernel<<<dim3(NTOK / 32), dim3(512), 0, stream>>>(emb, P4, lsum4,
                                                                     Wv, bv, d_out);
    } else if (ws_size >= needA) {
        int*      flag  = (int*)W;
        float*    lsumA = (float*)(W + 64);                          // 64 KB
        ushort_t* Wqkb  = (ushort_t*)(W + 64 + 65536);
        ushort_t* Wvb   = Wqkb + (size_t)DIM * DIM;
        ushort_t* bqkb  = Wvb + (size_t)DIM * DIM;
        ushort_t* bvb   = bqkb + DIM;
        ushort_t* embT  = bvb + DIM;
        ushort_t* Qws   = embT + (size_t)DIM * NTOK;
        ushort_t* P0    = Qws + (size_t)DIM * NTOK;
        ushort_t* P1    = P0 + (size_t)NTOK * DIM;

        detect_kernel<<<dim3(1), dim3(64), 0, stream>>>((const ushort_t*)emb, flag);
        prep_kernel<<<dim3(128), dim3(256), 0, stream>>>(flag, Wqk, bqk, Wv, bv,
                                                         Wqkb, bqkb, Wvb, bvb);
        projq_kernel<<<dim3(NTOK / 32), dim3(512), 0, stream>>>(flag, emb, Wqkb, bqkb, Qws);
        transpose_kernel<<<dim3(128, 8), dim3(256), 0, stream>>>(flag, emb, embT);
        attn64_kernel<<<dim3(256), dim3(1024), 0, stream>>>(Qws, embT, P0, P1, lsumA);
        finalize_kernel<<<dim3(NTOK / 64), dim3(512), 0, stream>>>(flag, P0, P1, lsumA,
                                                                   Wvb, bvb, d_out);
    } else if (ws_size >= needB) {
        int*      flag  = (int*)W;
        ushort_t* embT2 = (ushort_t*)(W + 64);
        ushort_t* Qws2  = embT2 + (size_t)DIM * NTOK;
        detect_kernel<<<dim3(1), dim3(64), 0, stream>>>((const ushort_t*)emb, flag);
        transpose_kernel<<<dim3(128, 8), dim3(256), 0, stream>>>(flag, emb, embT2);
        projq_kernel<<<dim3(NTOK / 32), dim3(512), 0, stream>>>(flag, emb, Wqk, bqk, Qws2);
        attn_fused_kernel<1><<<dim3(NTOK / 32), dim3(1024), 0, stream>>>(
            flag, Qws2, embT2, Wv, bv, d_out);
    } else {
        int*      flag  = (int*)W;
        ushort_t* Qsm = (ushort_t*)(W + 64);
        detect_kernel<<<dim3(1), dim3(64), 0, stream>>>((const ushort_t*)emb, flag);
        projq_kernel<<<dim3(NTOK / 32), dim3(512), 0, stream>>>(flag, emb, Wqk, bqk, Qsm);
        attn_fused_kernel<0><<<dim3(NTOK / 32), dim3(1024), 0, stream>>>(
            flag, Qsm, emb, Wv, bv, d_out);
    }
}

// Round 6
// 311.808 us; speedup vs baseline: 1.1036x; 1.1036x over previous
//
#include <hip/hip_runtime.h>
#include <hip/hip_bf16.h>

// N=8192, D=512.  Q = emb@Wqk^T+bqk (K==Q); out = softmax(QK^T/sqrt(512)) @ V.
// Softmax rows sum to 1 => out = (softmax(S)@emb) @ Wv^T + bv (V never built).
// R20: R19 regressed (344us): direct-fp32-weight reads doubled L2 weight
// bytes (256MB vs 128MB) and re-ran the RNE conversion 256x -> satellites
// 101->130us. R20 restores the R18-proven prep pipeline (one-time bf16
// weight conversion, coalesced) and keeps only R19's strictly-positive
// piece: the wave-uniform inline dtype probe, which removes the detect
// dispatch. Pipeline: prep2(probe) -> projqT3(probe, bf16 W) -> attn128
// (byte-identical R17/R18 core, 214us) -> finalize43(probe, bf16 W).
// Fallback tiers unchanged.

#define NTOK 8192
#define DIM  512

typedef unsigned short ushort_t;
typedef unsigned int u32;
typedef __attribute__((ext_vector_type(8))) __bf16 bf16x8;
typedef __attribute__((ext_vector_type(4))) float f32x4;

__device__ __forceinline__ float bf2f(ushort_t u) {
    union { unsigned int i; float f; } v; v.i = ((unsigned int)u) << 16; return v.f;
}
__device__ __forceinline__ ushort_t f2bf(float f) {
    union { float f; unsigned int i; } v; v.f = f;
    unsigned int b = v.i;
    return (ushort_t)((b + 0x7FFFu + ((b >> 16) & 1u)) >> 16);   // RNE
}
__device__ __forceinline__ __bf16 f2bfh(float f) {
    union { ushort_t u; __bf16 h; } c; c.u = f2bf(f); return c.h;
}
__device__ __forceinline__ f32x4 mfma16(bf16x8 a, bf16x8 b, f32x4 c) {
    return __builtin_amdgcn_mfma_f32_16x16x32_bf16(a, b, c, 0, 0, 0);
}
__device__ __forceinline__ bf16x8 load8(const void* p, size_t idx, bool f32) {
    if (f32) {
        const float* f = (const float*)p + idx;
        bf16x8 r;
        #pragma unroll
        for (int j = 0; j < 8; ++j) r[j] = f2bfh(f[j]);
        return r;
    }
    return *(const bf16x8*)((const ushort_t*)p + idx);
}
__device__ __forceinline__ float loadS(const void* p, size_t idx, bool f32) {
    return f32 ? ((const float*)p)[idx] : bf2f(((const ushort_t*)p)[idx]);
}
__device__ __forceinline__ void gload_lds16(const ushort_t* g, ushort_t* l) {
    __builtin_amdgcn_global_load_lds(
        (const __attribute__((address_space(1))) u32*)g,
        (__attribute__((address_space(3))) u32*)l, 16, 0, 0);
}

// Inline dtype probe: every wave samples the SAME 512 ushorts of emb ->
// identical count per wave -> block-uniform result, no cross-wave sync.
// Matches detect_kernel's heuristic exactly: f32 iff bf16-pattern cnt < 460.
__device__ __forceinline__ bool probe_f32(const ushort_t* emb) {
    int lane = threadIdx.x & 63;
    int cnt = 0;
    #pragma unroll
    for (int i = 0; i < 8; ++i) {
        ushort_t u = emb[(size_t)(lane * 8 + i) * 2];
        int a = u & 0x7FFF;
        int e = (u >> 7) & 0xFF;
        if (a == 0 || (e >= 111 && e <= 143)) cnt++;
    }
    cnt += __shfl_xor(cnt, 1);  cnt += __shfl_xor(cnt, 2);  cnt += __shfl_xor(cnt, 4);
    cnt += __shfl_xor(cnt, 8);  cnt += __shfl_xor(cnt, 16); cnt += __shfl_xor(cnt, 32);
    return cnt < 460;
}

#define LDA 520   // 260 dw, %32=4: uniform bank spread for b128 row reads
#define LDP 264

// ---------------------------------------------------------------------------
// Dtype probe kernel (fallback tiers only).
// ---------------------------------------------------------------------------
__global__ void detect_kernel(const ushort_t* __restrict__ emb, int* __restrict__ flag)
{
    int lane = threadIdx.x;
    int cnt = 0;
    #pragma unroll
    for (int i = 0; i < 8; ++i) {
        ushort_t u = emb[(size_t)(lane * 8 + i) * 2];
        int a = u & 0x7FFF;
        int e = (u >> 7) & 0xFF;
        if (a == 0 || (e >= 111 && e <= 143)) cnt++;
    }
    cnt += __shfl_xor(cnt, 1);  cnt += __shfl_xor(cnt, 2);  cnt += __shfl_xor(cnt, 4);
    cnt += __shfl_xor(cnt, 8);  cnt += __shfl_xor(cnt, 16); cnt += __shfl_xor(cnt, 32);
    if (lane == 0) *flag = (cnt >= 460) ? 1 : 0;
}

// ---------------------------------------------------------------------------
// prep2 (R20 top tier): inline probe + convert Wqk, Wv (512x512) + biases to
// bf16 in ws. 128 blocks x 256 thr. One-time, coalesced conversion.
// ---------------------------------------------------------------------------
__global__ __launch_bounds__(256)
void prep2_kernel(const ushort_t* __restrict__ emb,
                  const void* __restrict__ Wqk, const void* __restrict__ bqk,
                  const void* __restrict__ Wv,  const void* __restrict__ bv,
                  ushort_t* __restrict__ Wqkb, ushort_t* __restrict__ bqkb,
                  ushort_t* __restrict__ Wvb,  ushort_t* __restrict__ bvb)
{
    const bool f32 = probe_f32(emb);
    size_t gid = (size_t)blockIdx.x * 256 + threadIdx.x;   // 32768 threads
    size_t base = gid * 8;                                  // 262144 = 512*512
    *(bf16x8*)&Wqkb[base] = load8(Wqk, base, f32);
    *(bf16x8*)&Wvb[base]  = load8(Wv,  base, f32);
    if (gid < 64) {
        *(bf16x8*)&bqkb[base] = load8(bqk, base, f32);
        *(bf16x8*)&bvb[base]  = load8(bv,  base, f32);
    }
}

// ---------------------------------------------------------------------------
// prep (fallback tiers): flag-based version.
// ---------------------------------------------------------------------------
__global__ __launch_bounds__(256)
void prep_kernel(const int* __restrict__ flag,
                 const void* __restrict__ Wqk, const void* __restrict__ bqk,
                 const void* __restrict__ Wv,  const void* __restrict__ bv,
                 ushort_t* __restrict__ Wqkb, ushort_t* __restrict__ bqkb,
                 ushort_t* __restrict__ Wvb,  ushort_t* __restrict__ bvb)
{
    const bool f32 = (*flag == 0);
    size_t gid = (size_t)blockIdx.x * 256 + threadIdx.x;
    size_t base = gid * 8;
    *(bf16x8*)&Wqkb[base] = load8(Wqk, base, f32);
    *(bf16x8*)&Wvb[base]  = load8(Wv,  base, f32);
    if (gid < 64) {
        *(bf16x8*)&bqkb[base] = load8(bqk, base, f32);
        *(bf16x8*)&bvb[base]  = load8(bv,  base, f32);
    }
}

// ---------------------------------------------------------------------------
// projqT3 (R20 top tier): Q[32 rows] = emb@Wqk^T+bqk AND embT columns, from
// one staged tile. Inline probe for emb dtype; bf16 weights from ws.
// 256 blocks x 512 thr (8 waves); wave w owns cols [64w,+64).
// ---------------------------------------------------------------------------
__global__ __launch_bounds__(512)
void projqT3_kernel(const void* __restrict__ emb,
                    const ushort_t* __restrict__ Wb, const ushort_t* __restrict__ bb,
                    ushort_t* __restrict__ C, ushort_t* __restrict__ embT)
{
    __shared__ ushort_t Alds[32][LDA];   // 33,280 B
    const bool f32 = probe_f32((const ushort_t*)emb);
    const int tid  = threadIdx.x;
    const int wave = tid >> 6;
    const int lane = tid & 63;
    const int quad = lane >> 4;
    const int col  = lane & 15;
    const int mblk = blockIdx.x * 32;

    #pragma unroll
    for (int i = 0; i < 4; ++i) {
        int chunk = i * 512 + tid;
        int row = chunk >> 6;
        int k8  = (chunk & 63) * 8;
        *(bf16x8*)&Alds[row][k8] = load8(emb, (size_t)(mblk + row) * 512 + k8, f32);
    }
    __syncthreads();

    // ---- transpose store: thread t owns dim t, 32 tokens (64 B) ----
    {
        ushort_t buf[32];
        #pragma unroll
        for (int r = 0; r < 32; ++r) buf[r] = Alds[r][tid];
        ushort_t* dst = embT + (size_t)tid * NTOK + mblk;
        #pragma unroll
        for (int i = 0; i < 4; ++i)
            *(uint4*)(dst + i * 8) = *(uint4*)&buf[i * 8];
    }

    // ---- Q projection (32 rows x this wave's 64 cols), bf16 weights ----
    f32x4 acc[2][4];
    #pragma unroll
    for (int r = 0; r < 2; ++r)
        #pragma unroll
        for (int c = 0; c < 4; ++c) acc[r][c] = (f32x4){0.f, 0.f, 0.f, 0.f};

    const int wcol = wave * 64;
    #pragma unroll
    for (int kk = 0; kk < 16; ++kk) {
        bf16x8 a0 = *(const bf16x8*)&Alds[col][kk * 32 + quad * 8];
        bf16x8 a1 = *(const bf16x8*)&Alds[16 + col][kk * 32 + quad * 8];
        #pragma unroll
        for (int c = 0; c < 4; ++c) {
            bf16x8 b = *(const bf16x8*)&Wb[(size_t)(wcol + c * 16 + col) * 512
                                           + kk * 32 + quad * 8];
            acc[0][c] = mfma16(a0, b, acc[0][c]);
            acc[1][c] = mfma16(a1, b, acc[1][c]);
        }
    }

    #pragma unroll
    for (int r = 0; r < 2; ++r)
        #pragma unroll
        for (int c = 0; c < 4; ++c)
            #pragma unroll
            for (int g = 0; g < 4; ++g) {
                int m = mblk + r * 16 + quad * 4 + g;
                int n = wcol + c * 16 + col;
                C[(size_t)m * DIM + n] = f2bf(acc[r][c][g] + bf2f(bb[n]));
            }
}

// ---------------------------------------------------------------------------
// attn128 (R17-proven core + R18 XCD-aligned remap, byte-identical):
// 256 blocks = 64 q-tiles (Tq=128) x 4 key-quarters, 512 thr = 8 waves.
// ---------------------------------------------------------------------------
#define QT2  128
#define KT2  64
#define NIT2 32

__global__ __launch_bounds__(512, 2)
void attn128_kernel(const ushort_t* __restrict__ Q, const ushort_t* __restrict__ embT,
                    ushort_t* __restrict__ P, float* __restrict__ lsumA)
{
    __shared__ ushort_t Klds[2][KT2 * DIM];   // 131,072 B
    __shared__ ushort_t Plds[QT2 * KT2];      //  16,384 B (147,456 total)

    const int tid  = threadIdx.x;
    const int wave = tid >> 6;
    const int lane = tid & 63;
    const int quad = lane >> 4;
    const int col  = lane & 15;
    const int bid  = blockIdx.x;
    const int ks   = (bid & 7) >> 1;                      // XCD pair -> quarter
    const int qt   = ((bid >> 3) << 1) | (bid & 1);       // 0..63 bijective
    const int q0   = qt * QT2;
    const int kbase = ks * (NTOK / 4);
    ushort_t* Ps = P + (size_t)ks * NTOK * DIM;

    // Swizzle constants (K reads row=kt*16+col; P reads row=rt*16+col).
    const int s3 = col & 7;
    const int qo = (quad ^ (s3 & 3)) << 4;    // byte bits 4-5
    const int kx = (s3 >> 2) << 6;            // byte bit 6

    // ---- Q fragments: wave owns rows [q0+16w, +16), full K=512 (64 VGPR) ----
    bf16x8 qf[16];
    {
        const ushort_t* qrow = Q + (size_t)(q0 + wave * 16 + col) * DIM + quad * 8;
        #pragma unroll
        for (int kk = 0; kk < 16; ++kk)
            qf[kk] = *(const bf16x8*)(qrow + kk * 32);
    }

    // K-read byte bases per key-tile
    int rbk[4];
    #pragma unroll
    for (int kt = 0; kt < 4; ++kt)
        rbk[kt] = (((kt * 16 + col) << 10) | qo) ^ kx;

    const int pwrow = wave * 16 + quad * 4;          // P-write row base (+g)
    const int pb    = ((col << 7) | qo) ^ kx;        // PV-read byte base

    // ---- stage K(0) into buf 0 ----
    {
        const size_t gb = (size_t)kbase * DIM;
        #pragma unroll
        for (int i = 0; i < 8; ++i) {
            const int r = wave * 8 + i;
            gload_lds16(Q + gb + (size_t)r * DIM + ((lane ^ (r & 7)) << 3),
                        &Klds[0][r * DIM]);
        }
    }

    f32x4 accO[8][4];
    #pragma unroll
    for (int r = 0; r < 8; ++r)
        #pragma unroll
        for (int c = 0; c < 4; ++c) accO[r][c] = (f32x4){0.f, 0.f, 0.f, 0.f};
    float lsum[4] = {0.f, 0.f, 0.f, 0.f};

    const float sc = 0.04419417382415922f * 1.4426950408889634f;  // 1/sqrt(512)*log2e
    const int wd = wave * 64;

    for (int it = 0; it < NIT2; ++it) {
        const int cur = it & 1;
        const char* Kc = (const char*)&Klds[cur][0];
        const int j0 = kbase + it * KT2;

        // ---- prefetch K(t+1); counted vmcnt waits only for K(t)'s loads ----
        if (it + 1 < NIT2) {
            const size_t gb = (size_t)(j0 + KT2) * DIM;
            ushort_t* dst = &Klds[cur ^ 1][0];
            #pragma unroll
            for (int i = 0; i < 8; ++i) {
                const int r = wave * 8 + i;
                gload_lds16(Q + gb + (size_t)r * DIM + ((lane ^ (r & 7)) << 3),
                            dst + r * DIM);
            }
            asm volatile("s_waitcnt vmcnt(8)" ::: "memory");
        } else {
            asm volatile("s_waitcnt vmcnt(0)" ::: "memory");
        }
        // Top barrier: K(t) staged AND all waves done with P(t-1)
        __builtin_amdgcn_s_barrier();

        // ---- S = Q(wave's 16 rows) @ K(all 64 keys)^T, A from registers ----
        f32x4 accS[4];
        #pragma unroll
        for (int kt = 0; kt < 4; ++kt) accS[kt] = (f32x4){0.f, 0.f, 0.f, 0.f};
        __builtin_amdgcn_s_setprio(1);
        #pragma unroll
        for (int kk = 0; kk < 16; ++kk)
            #pragma unroll
            for (int kt = 0; kt < 4; ++kt) {
                bf16x8 kb = *(const bf16x8*)(Kc + (rbk[kt] ^ (kk << 6)));
                accS[kt] = mfma16(qf[kk], kb, accS[kt]);
            }
        __builtin_amdgcn_s_setprio(0);

        // ---- P = exp2(S*sc) -> swizzled Plds; row sums (rows wave-owned) ----
        #pragma unroll
        for (int kt = 0; kt < 4; ++kt)
            #pragma unroll
            for (int g = 0; g < 4; ++g) {
                float p = exp2f(fminf(accS[kt][g] * sc, 126.0f));
                lsum[g] += p;
                const int prow = pwrow + g;
                Plds[(prow << 6) | ((kt * 16 + col) ^ ((prow & 7) << 3))] = f2bf(p);
            }

        // ---- vb kslot 0 (global; latency hidden under exp + barrier) ----
        const ushort_t* eb = embT + (size_t)(wd + col) * NTOK + j0 + quad * 8;
        bf16x8 vb0[4];
        #pragma unroll
        for (int dt = 0; dt < 4; ++dt)
            vb0[dt] = *(const bf16x8*)(eb + (size_t)(dt * 16) * NTOK);

        // ---- B1: P visible (LDS only; K-prefetch stays in flight) ----
        asm volatile("s_waitcnt lgkmcnt(0)" ::: "memory");
        __builtin_amdgcn_s_barrier();

        // ---- PV kslot 0: O += P[:, 0:32] @ embT[:, 0:32]^T ----
        __builtin_amdgcn_s_setprio(1);
        #pragma unroll
        for (int rt = 0; rt < 8; ++rt) {
            bf16x8 pa = *(const bf16x8*)((const char*)Plds + (rt * 2048 + pb));
            #pragma unroll
            for (int dt = 0; dt < 4; ++dt)
                accO[rt][dt] = mfma16(pa, vb0[dt], accO[rt][dt]);
        }
        __builtin_amdgcn_s_setprio(0);

        // ---- vb kslot 1 + PV kslot 1 ----
        bf16x8 vb1[4];
        #pragma unroll
        for (int dt = 0; dt < 4; ++dt)
            vb1[dt] = *(const bf16x8*)(eb + (size_t)(dt * 16) * NTOK + 32);

        __builtin_amdgcn_s_setprio(1);
        #pragma unroll
        for (int rt = 0; rt < 8; ++rt) {
            bf16x8 pa = *(const bf16x8*)((const char*)Plds + (rt * 2048 + (pb ^ 64)));
            #pragma unroll
            for (int dt = 0; dt < 4; ++dt)
                accO[rt][dt] = mfma16(pa, vb1[dt], accO[rt][dt]);
        }
        __builtin_amdgcn_s_setprio(0);
        // No end barrier: next iter's top barrier fences P(t) vs P(t+1).
    }

    // ---- row sums: reduce over col lanes (keys); rows wave-owned ----
    #pragma unroll
    for (int g = 0; g < 4; ++g) {
        float s = lsum[g];
        s += __shfl_xor(s, 1);
        s += __shfl_xor(s, 2);
        s += __shfl_xor(s, 4);
        s += __shfl_xor(s, 8);
        if (col == 0)
            lsumA[(size_t)ks * NTOK + q0 + pwrow + g] = s;
    }

    // ---- store O partial (pre-normalization) ----
    #pragma unroll
    for (int rt = 0; rt < 8; ++rt)
        #pragma unroll
        for (int dt = 0; dt < 4; ++dt)
            #pragma unroll
            for (int g = 0; g < 4; ++g)
                Ps[(size_t)(q0 + rt * 16 + quad * 4 + g) * DIM + wd + dt * 16 + col]
                    = f2bf(accO[rt][dt][g]);
}

// ---------------------------------------------------------------------------
// finalize43 (R20 top tier): T = (P0..P3)/(l0..l3), out = T @ Wv^T + bv.
// Inline probe for out dtype; bf16 weights. 32-row tiles x 256 blocks.
// ---------------------------------------------------------------------------
__global__ __launch_bounds__(512)
void finalize43_kernel(const void* __restrict__ emb,
                       const ushort_t* __restrict__ P, const float* __restrict__ lsumA,
                       const ushort_t* __restrict__ Wb, const ushort_t* __restrict__ bb,
                       void* __restrict__ Out)
{
    __shared__ ushort_t Alds[32][LDA];
    const bool f32 = probe_f32((const ushort_t*)emb);
    const int tid  = threadIdx.x;
    const int wave = tid >> 6;
    const int lane = tid & 63;
    const int quad = lane >> 4;
    const int col  = lane & 15;
    const int mblk = blockIdx.x * 32;
    const size_t PSZ = (size_t)NTOK * DIM;

    #pragma unroll
    for (int i = 0; i < 4; ++i) {
        int chunk = i * 512 + tid;
        int row = chunk >> 6;
        int k8  = (chunk & 63) * 8;
        int m   = mblk + row;
        float rv = 1.0f / (lsumA[m] + lsumA[NTOK + m]
                         + lsumA[2 * NTOK + m] + lsumA[3 * NTOK + m]);
        size_t off = (size_t)m * 512 + k8;
        bf16x8 v0 = *(const bf16x8*)&P[off];
        bf16x8 v1 = *(const bf16x8*)&P[PSZ + off];
        bf16x8 v2 = *(const bf16x8*)&P[2 * PSZ + off];
        bf16x8 v3 = *(const bf16x8*)&P[3 * PSZ + off];
        bf16x8 t;
        #pragma unroll
        for (int j = 0; j < 8; ++j)
            t[j] = f2bfh(((float)v0[j] + (float)v1[j] + (float)v2[j] + (float)v3[j]) * rv);
        *(bf16x8*)&Alds[row][k8] = t;
    }
    __syncthreads();

    f32x4 acc[2][4];
    #pragma unroll
    for (int r = 0; r < 2; ++r)
        #pragma unroll
        for (int c = 0; c < 4; ++c) acc[r][c] = (f32x4){0.f, 0.f, 0.f, 0.f};

    const int wcol = wave * 64;
    #pragma unroll
    for (int kk = 0; kk < 16; ++kk) {
        bf16x8 a0 = *(const bf16x8*)&Alds[col][kk * 32 + quad * 8];
        bf16x8 a1 = *(const bf16x8*)&Alds[16 + col][kk * 32 + quad * 8];
        #pragma unroll
        for (int c = 0; c < 4; ++c) {
            bf16x8 b = *(const bf16x8*)&Wb[(size_t)(wcol + c * 16 + col) * 512
                                           + kk * 32 + quad * 8];
            acc[0][c] = mfma16(a0, b, acc[0][c]);
            acc[1][c] = mfma16(a1, b, acc[1][c]);
        }
    }

    #pragma unroll
    for (int r = 0; r < 2; ++r)
        #pragma unroll
        for (int c = 0; c < 4; ++c)
            #pragma unroll
            for (int g = 0; g < 4; ++g) {
                int m = mblk + r * 16 + quad * 4 + g;
                int n = wcol + c * 16 + col;
                float v = acc[r][c][g] + bf2f(bb[n]);
                if (f32) ((float*)Out)[(size_t)m * DIM + n] = v;
                else     ((ushort_t*)Out)[(size_t)m * DIM + n] = f2bf(v);
            }
}

// ---------------------------------------------------------------------------
// R13-proven attn64 + finalize (fallback for mid-size workspace).
// ---------------------------------------------------------------------------
__global__ __launch_bounds__(1024)
void attn64_kernel(const ushort_t* __restrict__ Q, const ushort_t* __restrict__ embT,
                   ushort_t* __restrict__ P0, ushort_t* __restrict__ P1,
                   float* __restrict__ lsumA)
{
    __shared__ ushort_t Qlds[64][LDA];
    __shared__ ushort_t Plds[2][64][LDP];
    __shared__ float    Lp[16][64];

    const int tid  = threadIdx.x;
    const int wave = tid >> 6;
    const int lane = tid & 63;
    const int quad = lane >> 4;
    const int col  = lane & 15;
    const int qt   = blockIdx.x & 127;
    const int ks   = blockIdx.x >> 7;
    const int q0   = qt * 64;
    const int kbase = ks * 4096;
    ushort_t* Ps = ks ? P1 : P0;

    #pragma unroll
    for (int i = 0; i < 4; ++i) {
        int chunk = i * 1024 + tid;
        int row = chunk >> 6;
        int k8  = (chunk & 63) * 8;
        *(bf16x8*)&Qlds[row][k8] = *(const bf16x8*)&Q[(size_t)(q0 + row) * 512 + k8];
    }
    __syncthreads();

    f32x4 accO[4][2];
    #pragma unroll
    for (int r = 0; r < 4; ++r)
        #pragma unroll
        for (int c = 0; c < 2; ++c) accO[r][c] = (f32x4){0.f, 0.f, 0.f, 0.f};

    float lsum[4][4];
    #pragma unroll
    for (int r = 0; r < 4; ++r)
        #pragma unroll
        for (int g = 0; g < 4; ++g) lsum[r][g] = 0.f;

    const float sc = 0.04419417382415922f * 1.4426950408889634f;
    const int wd = wave * 32;

    for (int it = 0; it < 16; ++it) {
        const int j0  = kbase + it * 256;
        const int buf = it & 1;

        f32x4 accS[4];
        #pragma unroll
        for (int r = 0; r < 4; ++r) accS[r] = (f32x4){0.f, 0.f, 0.f, 0.f};
        const size_t keyrow = (size_t)(j0 + wave * 16 + col) * 512;
        #pragma unroll
        for (int h = 0; h < 2; ++h) {
            bf16x8 kb[8];
            #pragma unroll
            for (int kk = 0; kk < 8; ++kk)
                kb[kk] = *(const bf16x8*)&Q[keyrow + (h * 8 + kk) * 32 + quad * 8];
            #pragma unroll
            for (int kk = 0; kk < 8; ++kk) {
                const int cofs = (h * 8 + kk) * 32 + quad * 8;
                #pragma unroll
                for (int r = 0; r < 4; ++r) {
                    bf16x8 a = *(const bf16x8*)&Qlds[r * 16 + col][cofs];
                    accS[r] = mfma16(a, kb[kk], accS[r]);
                }
            }
        }

        bf16x8 vbA[8];
        #pragma unroll
        for (int kk = 0; kk < 4; ++kk)
            #pragma unroll
            for (int c = 0; c < 2; ++c)
                vbA[kk * 2 + c] = *(const bf16x8*)&embT[
                    (size_t)(wd + c * 16 + col) * NTOK + j0 + kk * 32 + quad * 8];

        #pragma unroll
        for (int r = 0; r < 4; ++r)
            #pragma unroll
            for (int g = 0; g < 4; ++g) {
                float p = exp2f(fminf(accS[r][g] * sc, 126.0f));
                lsum[r][g] += p;
                Plds[buf][r * 16 + quad * 4 + g][wave * 16 + col] = f2bf(p);
            }

        bf16x8 vbB[8];
        #pragma unroll
        for (int kk = 0; kk < 4; ++kk)
            #pragma unroll
            for (int c = 0; c < 2; ++c)
                vbB[kk * 2 + c] = *(const bf16x8*)&embT[
                    (size_t)(wd + c * 16 + col) * NTOK + j0 + (4 + kk) * 32 + quad * 8];

        __syncthreads();

        #pragma unroll
        for (int kk = 0; kk < 4; ++kk) {
            #pragma unroll
            for (int r = 0; r < 4; ++r) {
                bf16x8 a = *(const bf16x8*)&Plds[buf][r * 16 + col][kk * 32 + quad * 8];
                #pragma unroll
                for (int c = 0; c < 2; ++c)
                    accO[r][c] = mfma16(a, vbA[kk * 2 + c], accO[r][c]);
            }
        }
        #pragma unroll
        for (int kk = 0; kk < 4; ++kk) {
            #pragma unroll
            for (int r = 0; r < 4; ++r) {
                bf16x8 a = *(const bf16x8*)&Plds[buf][r * 16 + col][(4 + kk) * 32 + quad * 8];
                #pragma unroll
                for (int c = 0; c < 2; ++c)
                    accO[r][c] = mfma16(a, vbB[kk * 2 + c], accO[r][c]);
            }
        }
    }

    #pragma unroll
    for (int r = 0; r < 4; ++r)
        #pragma unroll
        for (int g = 0; g < 4; ++g) {
            float s = lsum[r][g];
            s += __shfl_xor(s, 1);
            s += __shfl_xor(s, 2);
            s += __shfl_xor(s, 4);
            s += __shfl_xor(s, 8);
            if (col == 0)
                Lp[wave][r * 16 + quad * 4 + g] = s;
        }
    __syncthreads();
    if (tid < 64) {
        float t = 0.f;
        #pragma unroll
        for (int w = 0; w < 16; ++w) t += Lp[w][tid];
        lsumA[(size_t)ks * NTOK + q0 + tid] = t;
    }

    #pragma unroll
    for (int r = 0; r < 4; ++r)
        #pragma unroll
        for (int c = 0; c < 2; ++c)
            #pragma unroll
            for (int g = 0; g < 4; ++g)
                Ps[(size_t)(q0 + r * 16 + quad * 4 + g) * DIM + wd + c * 16 + col]
                    = f2bf(accO[r][c][g]);
}

__global__ __launch_bounds__(512)
void finalize_kernel(const int* __restrict__ flag,
                     const ushort_t* __restrict__ P0, const ushort_t* __restrict__ P1,
                     const float* __restrict__ lsumA,
                     const ushort_t* __restrict__ Wb, const ushort_t* __restrict__ bb,
                     void* __restrict__ Out)
{
    __shared__ ushort_t Alds[64][LDA];
    const bool f32 = (*flag == 0);
    const int tid  = threadIdx.x;
    const int wave = tid >> 6;
    const int lane = tid & 63;
    const int quad = lane >> 4;
    const int col  = lane & 15;
    const int mblk = blockIdx.x * 64;

    #pragma unroll
    for (int i = 0; i < 8; ++i) {
        int chunk = i * 512 + tid;
        int row = chunk >> 6;
        int k8  = (chunk & 63) * 8;
        int m   = mblk + row;
        float rv = 1.0f / (lsumA[m] + lsumA[NTOK + m]);
        bf16x8 v0 = *(const bf16x8*)&P0[(size_t)m * 512 + k8];
        bf16x8 v1 = *(const bf16x8*)&P1[(size_t)m * 512 + k8];
        bf16x8 t;
        #pragma unroll
        for (int j = 0; j < 8; ++j) t[j] = f2bfh(((float)v0[j] + (float)v1[j]) * rv);
        *(bf16x8*)&Alds[row][k8] = t;
    }
    __syncthreads();

    f32x4 acc[4][4];
    #pragma unroll
    for (int r = 0; r < 4; ++r)
        #pragma unroll
        for (int c = 0; c < 4; ++c) acc[r][c] = (f32x4){0.f, 0.f, 0.f, 0.f};

    const int wcol = wave * 64;
    #pragma unroll
    for (int kk = 0; kk < 16; ++kk) {
        bf16x8 a[4];
        #pragma unroll
        for (int r = 0; r < 4; ++r)
            a[r] = *(const bf16x8*)&Alds[r * 16 + col][kk * 32 + quad * 8];
        #pragma unroll
        for (int c = 0; c < 4; ++c) {
            bf16x8 b = *(const bf16x8*)&Wb[(size_t)(wcol + c * 16 + col) * 512
                                           + kk * 32 + quad * 8];
            #pragma unroll
            for (int r = 0; r < 4; ++r)
                acc[r][c] = mfma16(a[r], b, acc[r][c]);
        }
    }

    #pragma unroll
    for (int r = 0; r < 4; ++r)
        #pragma unroll
        for (int c = 0; c < 4; ++c)
            #pragma unroll
            for (int g = 0; g < 4; ++g) {
                int m = mblk + r * 16 + quad * 4 + g;
                int n = wcol + c * 16 + col;
                float v = acc[r][c][g] + bf2f(bb[n]);
                if (f32) ((float*)Out)[(size_t)m * DIM + n] = v;
                else     ((ushort_t*)Out)[(size_t)m * DIM + n] = f2bf(v);
            }
}

// ---------------------------------------------------------------------------
// Fallback kernels (R13-proven) for smaller workspaces.
// ---------------------------------------------------------------------------
__global__ __launch_bounds__(256)
void transpose_kernel(const int* __restrict__ flag, const void* __restrict__ emb,
                      ushort_t* __restrict__ embT)
{
    __shared__ float tile[64][65];
    const bool f32 = (*flag == 0);
    const int t  = threadIdx.x;
    const int j0 = blockIdx.x * 64;
    const int d0 = blockIdx.y * 64;
    {
        int r = t >> 2, cs = (t & 3) * 16;
        if (f32) {
            const float* src = (const float*)emb + (size_t)(j0 + r) * DIM + d0 + cs;
            #pragma unroll
            for (int i = 0; i < 16; i += 4) {
                float4 v = *(const float4*)(src + i);
                tile[r][cs + i]     = v.x;
                tile[r][cs + i + 1] = v.y;
                tile[r][cs + i + 2] = v.z;
                tile[r][cs + i + 3] = v.w;
            }
        } else {
            const ushort_t* src = (const ushort_t*)emb + (size_t)(j0 + r) * DIM + d0 + cs;
            #pragma unroll
            for (int i = 0; i < 16; ++i) tile[r][cs + i] = bf2f(src[i]);
        }
    }
    __syncthreads();
    {
        int d = t >> 2, js = (t & 3) * 16;
        ushort_t buf[16];
        #pragma unroll
        for (int i = 0; i < 16; ++i) buf[i] = f2bf(tile[js + i][d]);
        ushort_t* dst = embT + (size_t)(d0 + d) * NTOK + j0 + js;
        *(uint4*)dst       = *(uint4*)&buf[0];
        *(uint4*)(dst + 8) = *(uint4*)&buf[8];
    }
}

__global__ __launch_bounds__(512)
void projq_kernel(const int* __restrict__ flag, const void* __restrict__ emb,
                  const void* __restrict__ W, const void* __restrict__ bias,
                  ushort_t* __restrict__ C)
{
    __shared__ ushort_t Alds[32][LDA];
    const bool f32 = (*flag == 0);
    const int tid  = threadIdx.x;
    const int wave = tid >> 6;
    const int lane = tid & 63;
    const int quad = lane >> 4;
    const int col  = lane & 15;
    const int mblk = blockIdx.x * 32;

    #pragma unroll
    for (int i = 0; i < 4; ++i) {
        int chunk = i * 512 + tid;
        int row = chunk >> 6;
        int k8  = (chunk & 63) * 8;
        *(bf16x8*)&Alds[row][k8] = load8(emb, (size_t)(mblk + row) * 512 + k8, f32);
    }
    __syncthreads();

    f32x4 acc[2][4];
    #pragma unroll
    for (int r = 0; r < 2; ++r)
        #pragma unroll
        for (int c = 0; c < 4; ++c) acc[r][c] = (f32x4){0.f, 0.f, 0.f, 0.f};

    const int wcol = wave * 64;
    #pragma unroll
    for (int kk = 0; kk < 16; ++kk) {
        bf16x8 a0 = *(const bf16x8*)&Alds[col][kk * 32 + quad * 8];
        bf16x8 a1 = *(const bf16x8*)&Alds[16 + col][kk * 32 + quad * 8];
        #pragma unroll
        for (int c = 0; c < 4; ++c) {
            bf16x8 b = load8(W, (size_t)(wcol + c * 16 + col) * 512 + kk * 32 + quad * 8, f32);
            acc[0][c] = mfma16(a0, b, acc[0][c]);
            acc[1][c] = mfma16(a1, b, acc[1][c]);
        }
    }

    #pragma unroll
    for (int r = 0; r < 2; ++r)
        #pragma unroll
        for (int c = 0; c < 4; ++c)
            #pragma unroll
            for (int g = 0; g < 4; ++g) {
                int m = mblk + r * 16 + quad * 4 + g;
                int n = wcol + c * 16 + col;
                C[(size_t)m * DIM + n] = f2bf(acc[r][c][g] + loadS(bias, n, f32));
            }
}

template <int VT>
__global__ __launch_bounds__(1024)
void attn_fused_kernel(const int* __restrict__ flag, const ushort_t* __restrict__ Q,
                       const void* __restrict__ embOrT, const void* __restrict__ Wv,
                       const void* __restrict__ bv, void* __restrict__ Out)
{
    __shared__ ushort_t Qlds[32][LDA];
    __shared__ ushort_t Plds[2][32][LDP];
    __shared__ float    Lpart[16][32];

    const bool f32 = (*flag == 0);
    const int tid  = threadIdx.x;
    const int wave = tid >> 6;
    const int lane = tid & 63;
    const int quad = lane >> 4;
    const int col  = lane & 15;
    const int q0   = blockIdx.x * 32;

    #pragma unroll
    for (int i = 0; i < 2; ++i) {
        int chunk = i * 1024 + tid;
        int row = chunk >> 6;
        int k8  = (chunk & 63) * 8;
        *(bf16x8*)&Qlds[row][k8] = *(const bf16x8*)&Q[(size_t)(q0 + row) * 512 + k8];
    }
    __syncthreads();

    f32x4 accO[2][2];
    #pragma unroll
    for (int r = 0; r < 2; ++r)
        #pragma unroll
        for (int c = 0; c < 2; ++c) accO[r][c] = (f32x4){0.f, 0.f, 0.f, 0.f};

    float lsum[2][4];
    #pragma unroll
    for (int r = 0; r < 2; ++r)
        #pragma unroll
        for (int g = 0; g < 4; ++g) lsum[r][g] = 0.f;

    const float sc = 0.04419417382415922f * 1.4426950408889634f;
    const int wOcol = wave * 32;

    for (int it = 0; it < 32; ++it) {
        const int j0  = it * 256;
        const int buf = it & 1;

        bf16x8 kb[16];
        const size_t keyrow = (size_t)(j0 + wave * 16 + col) * 512;
        #pragma unroll
        for (int kk = 0; kk < 16; ++kk)
            kb[kk] = *(const bf16x8*)&Q[keyrow + kk * 32 + quad * 8];

        f32x4 accS[2];
        accS[0] = (f32x4){0.f, 0.f, 0.f, 0.f};
        accS[1] = (f32x4){0.f, 0.f, 0.f, 0.f};
        #pragma unroll
        for (int kk = 0; kk < 16; ++kk) {
            bf16x8 a0 = *(const bf16x8*)&Qlds[col][kk * 32 + quad * 8];
            bf16x8 a1 = *(const bf16x8*)&Qlds[16 + col][kk * 32 + quad * 8];
            accS[0] = mfma16(a0, kb[kk], accS[0]);
            accS[1] = mfma16(a1, kb[kk], accS[1]);
        }

        bf16x8 vb[16];
        #pragma unroll
        for (int kk = 0; kk < 8; ++kk)
            #pragma unroll
            for (int c = 0; c < 2; ++c) {
                if (VT) {
                    vb[kk * 2 + c] = *(const bf16x8*)((const ushort_t*)embOrT
                        + (size_t)(wOcol + c * 16 + col) * NTOK + j0 + kk * 32 + quad * 8);
                } else {
                    size_t base = (size_t)(j0 + kk * 32 + quad * 8) * 512 + (wOcol + c * 16 + col);
                    bf16x8 b;
                    if (f32) {
                        const float* bp = (const float*)embOrT + base;
                        #pragma unroll
                        for (int j = 0; j < 8; ++j) b[j] = f2bfh(bp[(size_t)j * 512]);
                    } else {
                        const __bf16* bp = (const __bf16*)embOrT + base;
                        #pragma unroll
                        for (int j = 0; j < 8; ++j) b[j] = bp[(size_t)j * 512];
                    }
                    vb[kk * 2 + c] = b;
                }
            }

        #pragma unroll
        for (int r = 0; r < 2; ++r)
            #pragma unroll
            for (int g = 0; g < 4; ++g) {
                float p = exp2f(fminf(accS[r][g] * sc, 126.0f));
                lsum[r][g] += p;
                Plds[buf][r * 16 + quad * 4 + g][wave * 16 + col] = f2bf(p);
            }

        __syncthreads();

        #pragma unroll
        for (int kk = 0; kk < 8; ++kk) {
            bf16x8 a0 = *(const bf16x8*)&Plds[buf][col][kk * 32 + quad * 8];
            bf16x8 a1 = *(const bf16x8*)&Plds[buf][16 + col][kk * 32 + quad * 8];
            #pragma unroll
            for (int c = 0; c < 2; ++c) {
                accO[0][c] = mfma16(a0, vb[kk * 2 + c], accO[0][c]);
                accO[1][c] = mfma16(a1, vb[kk * 2 + c], accO[1][c]);
            }
        }
    }

    #pragma unroll
    for (int r = 0; r < 2; ++r)
        #pragma unroll
        for (int g = 0; g < 4; ++g) {
            float s = lsum[r][g];
            s += __shfl_xor(s, 1);
            s += __shfl_xor(s, 2);
            s += __shfl_xor(s, 4);
            s += __shfl_xor(s, 8);
            lsum[r][g] = s;
        }
    if (col == 0) {
        #pragma unroll
        for (int r = 0; r < 2; ++r)
            #pragma unroll
            for (int g = 0; g < 4; ++g)
                Lpart[wave][r * 16 + quad * 4 + g] = lsum[r][g];
    }
    __syncthreads();

    #pragma unroll
    for (int r = 0; r < 2; ++r) {
        float rinv[4];
        #pragma unroll
        for (int g = 0; g < 4; ++g) {
            float t = 0.f;
            #pragma unroll
            for (int w = 0; w < 16; ++w) t += Lpart[w][r * 16 + quad * 4 + g];
            rinv[g] = 1.0f / t;
        }
        #pragma unroll
        for (int c = 0; c < 2; ++c)
            #pragma unroll
            for (int g = 0; g < 4; ++g)
                Qlds[r * 16 + quad * 4 + g][wOcol + c * 16 + col] = f2bf(accO[r][c][g] * rinv[g]);
    }
    __syncthreads();

    f32x4 acc2[2][2];
    #pragma unroll
    for (int r = 0; r < 2; ++r)
        #pragma unroll
        for (int c = 0; c < 2; ++c) acc2[r][c] = (f32x4){0.f, 0.f, 0.f, 0.f};

    #pragma unroll
    for (int kk = 0; kk < 16; ++kk) {
        bf16x8 a0 = *(const bf16x8*)&Qlds[col][kk * 32 + quad * 8];
        bf16x8 a1 = *(const bf16x8*)&Qlds[16 + col][kk * 32 + quad * 8];
        #pragma unroll
        for (int c = 0; c < 2; ++c) {
            bf16x8 b = load8(Wv, (size_t)(wOcol + c * 16 + col) * 512 + kk * 32 + quad * 8, f32);
            acc2[0][c] = mfma16(a0, b, acc2[0][c]);
            acc2[1][c] = mfma16(a1, b, acc2[1][c]);
        }
    }

    #pragma unroll
    for (int r = 0; r < 2; ++r)
        #pragma unroll
        for (int c = 0; c < 2; ++c)
            #pragma unroll
            for (int g = 0; g < 4; ++g) {
                int m = q0 + r * 16 + quad * 4 + g;
                int n = wOcol + c * 16 + col;
                float v = acc2[r][c][g] + loadS(bv, n, f32);
                if (f32) ((float*)Out)[(size_t)m * DIM + n] = v;
                else     ((ushort_t*)Out)[(size_t)m * DIM + n] = f2bf(v);
            }
}

extern "C" void kernel_launch(void* const* d_in, const int* in_sizes, int n_in,
                              void* d_out, int out_size, void* d_ws, size_t ws_size,
                              hipStream_t stream)
{
    const void* emb = d_in[0];
    const void* Wqk = d_in[1];
    const void* bqk = d_in[2];
    const void* Wv  = d_in[3];
    const void* bv  = d_in[4];

    char* W = (char*)d_ws;

    // R20 top-tier layout: pad(64) | lsum4 (128KB) | Wqkb | Wvb | bqkb | bvb |
    // embT | Qws | P[4]
    const size_t needC = 64 + 4 * (size_t)NTOK * 4 + 2 * (size_t)DIM * DIM * 2
                       + 2 * DIM * 2 + 6 * (size_t)NTOK * DIM * 2;   // ~49.1 MB
    // Old (R14) layout for mid tier
    const size_t needA = 64 + 65536 + 2 * (size_t)DIM * DIM * 2 + 2 * DIM * 2
                       + 4 * (size_t)NTOK * DIM * 2;                  // ~33.1 MB
    const size_t needB = 64 + 2 * (size_t)NTOK * DIM * 2;             // 16.03 MB

    if (ws_size >= needC) {
        float*    lsum4 = (float*)(W + 64);                          // 128 KB
        ushort_t* Wqkb  = (ushort_t*)(W + 64 + 4 * (size_t)NTOK * 4);
        ushort_t* Wvb   = Wqkb + (size_t)DIM * DIM;
        ushort_t* bqkb  = Wvb + (size_t)DIM * DIM;
        ushort_t* bvb   = bqkb + DIM;
        ushort_t* embT  = bvb + DIM;                                 // 8 MB
        ushort_t* Qws   = embT + (size_t)DIM * NTOK;                 // 8 MB
        ushort_t* P4    = Qws + (size_t)DIM * NTOK;                  // 4 x 8 MB

        prep2_kernel<<<dim3(128), dim3(256), 0, stream>>>(
            (const ushort_t*)emb, Wqk, bqk, Wv, bv, Wqkb, bqkb, Wvb, bvb);
        projqT3_kernel<<<dim3(NTOK / 32), dim3(512), 0, stream>>>(emb, Wqkb, bqkb,
                                                                  Qws, embT);
        attn128_kernel<<<dim3(256), dim3(512), 0, stream>>>(Qws, embT, P4, lsum4);
        finalize43_kernel<<<dim3(NTOK / 32), dim3(512), 0, stream>>>(emb, P4, lsum4,
                                                                     Wvb, bvb, d_out);
    } else if (ws_size >= needA) {
        int*      flag  = (int*)W;
        float*    lsumA = (float*)(W + 64);                          // 64 KB
        ushort_t* Wqkb  = (ushort_t*)(W + 64 + 65536);
        ushort_t* Wvb   = Wqkb + (size_t)DIM * DIM;
        ushort_t* bqkb  = Wvb + (size_t)DIM * DIM;
        ushort_t* bvb   = bqkb + DIM;
        ushort_t* embT  = bvb + DIM;
        ushort_t* Qws   = embT + (size_t)DIM * NTOK;
        ushort_t* P0    = Qws + (size_t)DIM * NTOK;
        ushort_t* P1    = P0 + (size_t)NTOK * DIM;

        detect_kernel<<<dim3(1), dim3(64), 0, stream>>>((const ushort_t*)emb, flag);
        prep_kernel<<<dim3(128), dim3(256), 0, stream>>>(flag, Wqk, bqk, Wv, bv,
                                                         Wqkb, bqkb, Wvb, bvb);
        projq_kernel<<<dim3(NTOK / 32), dim3(512), 0, stream>>>(flag, emb, Wqkb, bqkb, Qws);
        transpose_kernel<<<dim3(128, 8), dim3(256), 0, stream>>>(flag, emb, embT);
        attn64_kernel<<<dim3(256), dim3(1024), 0, stream>>>(Qws, embT, P0, P1, lsumA);
        finalize_kernel<<<dim3(NTOK / 64), dim3(512), 0, stream>>>(flag, P0, P1, lsumA,
                                                                   Wvb, bvb, d_out);
    } else if (ws_size >= needB) {
        int*      flag  = (int*)W;
        ushort_t* embT2 = (ushort_t*)(W + 64);
        ushort_t* Qws2  = embT2 + (size_t)DIM * NTOK;
        detect_kernel<<<dim3(1), dim3(64), 0, stream>>>((const ushort_t*)emb, flag);
        transpose_kernel<<<dim3(128, 8), dim3(256), 0, stream>>>(flag, emb, embT2);
        projq_kernel<<<dim3(NTOK / 32), dim3(512), 0, stream>>>(flag, emb, Wqk, bqk, Qws2);
        attn_fused_kernel<1><<<dim3(NTOK / 32), dim3(1024), 0, stream>>>(
            flag, Qws2, embT2, Wv, bv, d_out);
    } else {
        int*      flag  = (int*)W;
        ushort_t* Qsm = (ushort_t*)(W + 64);
        detect_kernel<<<dim3(1), dim3(64), 0, stream>>>((const ushort_t*)emb, flag);
        projq_kernel<<<dim3(NTOK / 32), dim3(512), 0, stream>>>(flag, emb, Wqk, bqk, Qsm);
        attn_fused_kernel<0><<<dim3(NTOK / 32), dim3(1024), 0, stream>>>(
            flag, Qsm, emb, Wv, bv, d_out);
    }
}